// Round 4
// baseline (605.960 us; speedup 1.0000x reference)
//
#include <hip/hip_runtime.h>
#include <stdint.h>
#include <stddef.h>

// ---------------------------------------------------------------------------
// TinySelfAttention on MI355X (gfx950), bf16 MFMA pipeline:
//   1) cast x -> bf16
//   2) transpose+cast W_qkv, W_out -> bf16 B^T form
//   3) gemm_qkv: 256x384 tile (grid 16x16 = 256 blocks = EXACTLY 1/CU, no
//      tail), BK=64, 8 waves (2m x 4n, per-wave 128x96 = 298B LDS/MFMA),
//      2-buf LDS (160KiB exactly), 4 phases/K-tile x 24 MFMA, counted
//      vmcnt(5)/(2) (never 0), XOR-swizzled LDS, setprio, raw s_barrier.
//      Q cols pre-scaled; V cols (n>=4096, incl. straddle tile) written as
//      per-head V^T via LDS transpose.
//   4) flash attention v6: 512-thread blocks, 128-row Q tile, 64-col K/V
//      tiles double-buffered, 1 barrier/iter, wave-private P, no-max
//      softmax, ones-MFMA row sums. 2 blocks/CU.
//   5) GEMM 256x128 (round-1 pipeline): y = O @ W_out + b_out (fp32 out)
// ---------------------------------------------------------------------------

typedef __attribute__((ext_vector_type(8))) short bf16x8;   // 8 x bf16 = 4 VGPRs
typedef __attribute__((ext_vector_type(4))) float f32x4;    // MFMA accumulator

#define SOFT_SCALE 0.12751743075419806f  // (1/sqrt(128)) * log2(e)

__device__ __forceinline__ short f2bf(float f) {
  union { float f; unsigned u; } v; v.f = f;
  unsigned u = v.u + 0x7fffu + ((v.u >> 16) & 1u);  // RNE
  return (short)(u >> 16);
}

__device__ __forceinline__ void gload_lds16(const void* g, const void* l) {
  // async global->LDS, 16B per lane; LDS dest = wave-uniform base + lane*16
  __builtin_amdgcn_global_load_lds(
      (__attribute__((address_space(1))) void*)(uintptr_t)g,
      (__attribute__((address_space(3))) void*)(uintptr_t)l,
      16, 0, 0);
}

// ---------------------------------------------------------------------------
// Kernel 1: fp32 -> bf16 cast, 8 elems/thread
// ---------------------------------------------------------------------------
__global__ __launch_bounds__(256) void cast_f32_bf16(
    const float* __restrict__ in, short* __restrict__ out, int n8) {
  int i = blockIdx.x * 256 + threadIdx.x;
  if (i >= n8) return;
  float4 a = ((const float4*)in)[i * 2];
  float4 b = ((const float4*)in)[i * 2 + 1];
  bf16x8 o;
  o[0] = f2bf(a.x); o[1] = f2bf(a.y); o[2] = f2bf(a.z); o[3] = f2bf(a.w);
  o[4] = f2bf(b.x); o[5] = f2bf(b.y); o[6] = f2bf(b.z); o[7] = f2bf(b.w);
  ((bf16x8*)out)[i] = o;
}

// ---------------------------------------------------------------------------
// Kernel 2: W [K][N] fp32 -> WT [N][K] bf16, 32x32 tiles
// ---------------------------------------------------------------------------
__global__ __launch_bounds__(256) void transpose_cast_w(
    const float* __restrict__ W, short* __restrict__ WT, int K, int N) {
  __shared__ short t[32][33];
  int k0 = blockIdx.x * 32, n0 = blockIdx.y * 32;
  int r = threadIdx.x >> 3;
  int c = (threadIdx.x & 7) * 4;
  float4 v = *(const float4*)(W + (size_t)(k0 + r) * N + n0 + c);
  t[r][c + 0] = f2bf(v.x); t[r][c + 1] = f2bf(v.y);
  t[r][c + 2] = f2bf(v.z); t[r][c + 3] = f2bf(v.w);
  __syncthreads();
  short4 o;
  o.x = t[c + 0][r]; o.y = t[c + 1][r]; o.z = t[c + 2][r]; o.w = t[c + 3][r];
  *(short4*)(WT + (size_t)(n0 + r) * K + k0 + c) = o;
}

// ---------------------------------------------------------------------------
// Kernel 3: gemm_qkv  C[M][6144] = A[M][K] @ BT[6144][K]^T + bias
//
// BM=256, BN=384, BK=64, 512 thr = 8 waves as 2(m) x 4(n), per-wave 128x96.
// Grid (16,16) = 256 blocks = exactly 1 block/CU (LDS 160 KiB), no tail.
// LDS: 2 bufs x (A 32KiB + B 48KiB). Per K-tile per wave: stage 10 chunks
// (1KiB each) for tile t+1, issued per phase in order [Ae(2),B1(3),Ao(2),
// B2(3)]. Phase read needs (queue-simulated):
//   ph0: af0 rows [0,64)  (Ae) + bf[0..2] rows [0,48)  (B1) -> vmcnt(5)
//   ph1: bf[3..5] rows [48,96) (B2)                          -> vmcnt(2)
//        (also completes Ao -> ph2 needs no wait)
//   ph2: af1 rows [64,128) (Ao)                              -> none
//   ph3: register reuse only                                 -> none
// Never drains to 0 in the loop. 24 MFMA per phase.
// Chunk ownership: A (32 chunks): wave w owns {w, w+16 | w+8, w+24}.
//   B (48 chunks): B1 list idx i=3w..3w+2, chunk=12*(i/6)+(i%6); B2 = +6.
// XOR swizzle on 128B rows: src col16 ^= row&7; read slot ^= l16&7.
// Epilogue: Q cols (n<2048) pre-scaled; C written for n<4096; V cols
// (n>=4096, up to 3 heads/tile; straddle tile n0=3840 contributes head 0)
// transposed through LDS T[128][264] per head -> vT[bh][d][s].
// ---------------------------------------------------------------------------
__global__ __launch_bounds__(512, 2) void gemm_qkv(
    const short* __restrict__ A, const short* __restrict__ BT,
    short* __restrict__ C, const float* __restrict__ bias,
    short* __restrict__ vTout, int M, int N, int K) {
  (void)M;
  __shared__ __align__(16) short SH[81920];  // 163840 B = 2 x (32K + 48K)
  const int tid = threadIdx.x;
  const int wave = tid >> 6, lane = tid & 63;
  const int quad = lane >> 4, l16 = lane & 15;
  const int wm = wave >> 2, wn = wave & 3;   // 2 x 4 wave grid
  const int kx = (l16 & 7) << 3;             // read-side swizzle key (shorts)

  // XCD-aware bijective swizzle (nwg = 256, %8 == 0)
  const int gx = gridDim.x;
  int bid = blockIdx.y * gx + blockIdx.x;
  const int nwg = gx * gridDim.y;
  bid = (bid & 7) * (nwg >> 3) + (bid >> 3);
  const int m0 = (bid % gx) * 256, n0 = (bid / gx) * 384;

  // staging: chunk = 8 rows x 64 cols = 1 KiB, one gload_lds16 per wave.
  const int rsub = lane >> 3;                 // row within 8-row chunk
  const int csub = ((lane & 7) ^ rsub) << 3;  // pre-swizzled col (shorts)
  const int cA[4] = {wave, wave + 16, wave + 8, wave + 24};  // [Ae | Ao]
  int cB[6];
#pragma unroll
  for (int j = 0; j < 3; ++j) {
    int i = wave * 3 + j;
    cB[j] = 12 * (i / 6) + (i % 6);      // B1
    cB[3 + j] = cB[j] + 6;               // B2
  }
  const short* aP[4];
  const short* bP[6];
#pragma unroll
  for (int i = 0; i < 4; ++i)
    aP[i] = A + (size_t)(m0 + cA[i] * 8 + rsub) * K + csub;
#pragma unroll
  for (int j = 0; j < 6; ++j)
    bP[j] = BT + (size_t)(n0 + cB[j] * 8 + rsub) * K + csub;

  // stage one group: g = 0:Ae(2), 1:B1(3), 2:Ao(2), 3:B2(3)
  auto stage = [&](int g, int st, int sbuf) {
    char* base = (char*)SH + sbuf * 81920;
    if (g == 0 || g == 2) {
      int i0 = (g == 0) ? 0 : 2;
#pragma unroll
      for (int i = 0; i < 2; ++i)
        gload_lds16(aP[i0 + i] + st * 64, base + cA[i0 + i] * 1024);
    } else {
      int j0 = (g == 1) ? 0 : 3;
#pragma unroll
      for (int j = 0; j < 3; ++j)
        gload_lds16(bP[j0 + j] + st * 64, base + 32768 + cB[j0 + j] * 1024);
    }
  };

  // prologue: tile 0, order [Ae, B1, Ao, B2] (10 loads/wave outstanding)
  stage(0, 0, 0); stage(1, 0, 0); stage(2, 0, 0); stage(3, 0, 0);

  f32x4 acc[8][6] = {};
  const int nT = K >> 6;
  for (int t = 0; t < nT; ++t) {
    const int st = (t + 1 < nT) ? (t + 1) : (nT - 1);  // clamp: uniform vmcnt
    const int sbuf = (t + 1) & 1;
    const short* As = SH + (t & 1) * 40960;
    const short* Bs = As + 16384;
    bf16x8 bf[6][2];

    // ---- phase 0: read af0(8) + bf[0..2](6) | stage Ae(t+1) | 24 MFMA ----
    asm volatile("s_waitcnt vmcnt(5)" ::: "memory");
    __builtin_amdgcn_s_barrier();
    bf16x8 af0[4][2];
#pragma unroll
    for (int f = 0; f < 4; ++f) {
      const int row = wm * 128 + f * 16 + l16;
#pragma unroll
      for (int kk = 0; kk < 2; ++kk)
        af0[f][kk] = *(const bf16x8*)(As + row * 64 +
                                      (((kk << 5) | (quad << 3)) ^ kx));
    }
#pragma unroll
    for (int u = 0; u < 3; ++u) {
      const int row = wn * 96 + u * 16 + l16;
#pragma unroll
      for (int kk = 0; kk < 2; ++kk)
        bf[u][kk] = *(const bf16x8*)(Bs + row * 64 +
                                     (((kk << 5) | (quad << 3)) ^ kx));
    }
    stage(0, st, sbuf);
    __builtin_amdgcn_s_barrier();
    asm volatile("s_waitcnt lgkmcnt(0)" ::: "memory");
    __builtin_amdgcn_sched_barrier(0);
    __builtin_amdgcn_s_setprio(1);
#pragma unroll
    for (int f = 0; f < 4; ++f)
#pragma unroll
      for (int u = 0; u < 3; ++u)
#pragma unroll
        for (int kk = 0; kk < 2; ++kk)
          acc[f][u] = __builtin_amdgcn_mfma_f32_16x16x32_bf16(
              af0[f][kk], bf[u][kk], acc[f][u], 0, 0, 0);
    __builtin_amdgcn_s_setprio(0);

    // ---- phase 1: read bf[3..5](6) | stage B1(t+1) | 24 MFMA ----
    asm volatile("s_waitcnt vmcnt(2)" ::: "memory");
    __builtin_amdgcn_s_barrier();
#pragma unroll
    for (int u = 0; u < 3; ++u) {
      const int row = wn * 96 + 48 + u * 16 + l16;
#pragma unroll
      for (int kk = 0; kk < 2; ++kk)
        bf[3 + u][kk] = *(const bf16x8*)(Bs + row * 64 +
                                         (((kk << 5) | (quad << 3)) ^ kx));
    }
    stage(1, st, sbuf);
    __builtin_amdgcn_s_barrier();
    asm volatile("s_waitcnt lgkmcnt(0)" ::: "memory");
    __builtin_amdgcn_sched_barrier(0);
    __builtin_amdgcn_s_setprio(1);
#pragma unroll
    for (int f = 0; f < 4; ++f)
#pragma unroll
      for (int u = 0; u < 3; ++u)
#pragma unroll
        for (int kk = 0; kk < 2; ++kk)
          acc[f][3 + u] = __builtin_amdgcn_mfma_f32_16x16x32_bf16(
              af0[f][kk], bf[3 + u][kk], acc[f][3 + u], 0, 0, 0);
    __builtin_amdgcn_s_setprio(0);

    // ---- phase 2: read af1(8) | stage Ao(t+1) | 24 MFMA ----
    __builtin_amdgcn_s_barrier();
    bf16x8 af1[4][2];
#pragma unroll
    for (int f = 0; f < 4; ++f) {
      const int row = wm * 128 + 64 + f * 16 + l16;
#pragma unroll
      for (int kk = 0; kk < 2; ++kk)
        af1[f][kk] = *(const bf16x8*)(As + row * 64 +
                                      (((kk << 5) | (quad << 3)) ^ kx));
    }
    stage(2, st, sbuf);
    __builtin_amdgcn_s_barrier();
    asm volatile("s_waitcnt lgkmcnt(0)" ::: "memory");
    __builtin_amdgcn_sched_barrier(0);
    __builtin_amdgcn_s_setprio(1);
#pragma unroll
    for (int f = 0; f < 4; ++f)
#pragma unroll
      for (int u = 0; u < 3; ++u)
#pragma unroll
        for (int kk = 0; kk < 2; ++kk)
          acc[4 + f][u] = __builtin_amdgcn_mfma_f32_16x16x32_bf16(
              af1[f][kk], bf[u][kk], acc[4 + f][u], 0, 0, 0);
    __builtin_amdgcn_s_setprio(0);

    // ---- phase 3: stage B2(t+1) | 24 MFMA (register reuse) ----
    __builtin_amdgcn_s_barrier();
    stage(3, st, sbuf);
    __builtin_amdgcn_s_setprio(1);
#pragma unroll
    for (int f = 0; f < 4; ++f)
#pragma unroll
      for (int u = 0; u < 3; ++u)
#pragma unroll
        for (int kk = 0; kk < 2; ++kk)
          acc[4 + f][3 + u] = __builtin_amdgcn_mfma_f32_16x16x32_bf16(
              af1[f][kk], bf[3 + u][kk], acc[4 + f][3 + u], 0, 0, 0);
    __builtin_amdgcn_s_setprio(0);
  }

  // drain outstanding clamped prefetch DMAs before LDS reuse / exit
  asm volatile("s_waitcnt vmcnt(0)" ::: "memory");
  __builtin_amdgcn_s_barrier();

  // ---- C write for Q/K columns (n < 4096); Q cols scaled ----
  if (n0 < 4096) {
#pragma unroll
    for (int j = 0; j < 6; ++j) {
      const int n = n0 + wn * 96 + j * 16 + l16;
      if (n < 4096) {
        const float bv = bias[n];
#pragma unroll
        for (int f = 0; f < 8; ++f) {
          const int mb = m0 + wm * 128 + f * 16 + quad * 4;
#pragma unroll
          for (int r = 0; r < 4; ++r) {
            float v = acc[f][j][r] + bv;
            if (n < 2048) v *= SOFT_SCALE;
            C[(size_t)(mb + r) * N + n] = f2bf(v);
          }
        }
      }
    }
  }

  // ---- V^T epilogue: heads fully inside [4096, n0+384) ----
  if (n0 + 384 > 4096) {
    short* T = (short*)SH;
    const int b = m0 >> 11, s0 = m0 & 2047;
#pragma unroll
    for (int hh = 0; hh < 3; ++hh) {
      const int nlb = hh * 128;
      const int gcol = n0 + nlb;
      if (gcol < 4096) continue;  // block-uniform
      const int hg = (gcol - 4096) >> 7;
      // write phase: fragments with nl in [nlb, nlb+128)
#pragma unroll
      for (int j = 0; j < 6; ++j) {
        const int nl = wn * 96 + j * 16 + l16;
        if (nl >= nlb && nl < nlb + 128) {
          const float bv = bias[n0 + nl];
#pragma unroll
          for (int f = 0; f < 8; ++f) {
            const int ml = wm * 128 + f * 16 + quad * 4;
            short4 o;
            o.x = f2bf(acc[f][j][0] + bv);
            o.y = f2bf(acc[f][j][1] + bv);
            o.z = f2bf(acc[f][j][2] + bv);
            o.w = f2bf(acc[f][j][3] + bv);
            *(short4*)(T + (nl - nlb) * 264 + ml) = o;
          }
        }
      }
      __builtin_amdgcn_s_barrier();
      // copy phase: 128 rows x 256 cols -> vT[(b*16+hg)*128 + d][s0..]
#pragma unroll
      for (int pass = 0; pass < 8; ++pass) {
        const int row = pass * 16 + (tid >> 5);
        const int c = (tid & 31) * 8;
        bf16x8 v = *(const bf16x8*)(T + row * 264 + c);
        *(bf16x8*)(vTout + ((size_t)((b * 16 + hg) * 128 + row)) * 2048 + s0 +
                   c) = v;
      }
      __builtin_amdgcn_s_barrier();
    }
  }
}

// ---------------------------------------------------------------------------
// Kernel 3b: GEMM 256x128 (round-1 pipeline) for the output projection.
// 8 waves 4(m) x 2(n), per-wave 64x64, 3-buf LDS, counted vmcnt(6).
// ---------------------------------------------------------------------------
__global__ __launch_bounds__(512, 2) void gemm_out(
    const short* __restrict__ A, const short* __restrict__ BT,
    float* __restrict__ C, const float* __restrict__ bias, int M, int N,
    int K) {
  (void)M;
  __shared__ __align__(16) short SH[73728];  // 147456 B = 3 x 49152
  const int tid = threadIdx.x;
  const int wave = tid >> 6, lane = tid & 63;
  const int quad = lane >> 4, l16 = lane & 15;
  const int wm = wave >> 1, wn = wave & 1;   // 4 x 2 wave grid
  const int kx = (l16 & 7) << 3;

  const int gx = gridDim.x;
  int bid = blockIdx.y * gx + blockIdx.x;
  const int nwg = gx * gridDim.y;
  bid = (bid & 7) * (nwg >> 3) + (bid >> 3);
  const int m0 = (bid % gx) * 256, n0 = (bid / gx) * 128;

  const int rsub = lane >> 3;
  const int csub = ((lane & 7) ^ rsub) << 3;
  const short* aS[4];
  const short* bS[2];
#pragma unroll
  for (int i = 0; i < 4; ++i)
    aS[i] = A + (size_t)(m0 + (wave * 4 + i) * 8 + rsub) * K + csub;
#pragma unroll
  for (int i = 0; i < 2; ++i)
    bS[i] = BT + (size_t)(n0 + (wave * 2 + i) * 8 + rsub) * K + csub;

  auto stageA = [&](int st, int sb) {
#pragma unroll
    for (int i = 0; i < 4; ++i)
      gload_lds16(aS[i] + st * 64,
                  (const char*)SH + sb * 49152 + (wave * 4 + i) * 1024);
  };
  auto stageB = [&](int st, int sb) {
#pragma unroll
    for (int i = 0; i < 2; ++i)
      gload_lds16(bS[i] + st * 64,
                  (const char*)SH + sb * 49152 + 32768 + (wave * 2 + i) * 1024);
  };

  stageA(0, 0); stageB(0, 0);
  stageA(1, 1); stageB(1, 1);

  f32x4 acc[4][4] = {};
  const int nT = K >> 6;
  int buf = 0, sb = 2;
  for (int t = 0; t < nT; ++t) {
    const int st = (t + 2 < nT) ? (t + 2) : (nT - 1);
    const short* As = (const short*)((const char*)SH + buf * 49152);
    const short* Bs = As + 16384;

    asm volatile("s_waitcnt vmcnt(6)" ::: "memory");
    __builtin_amdgcn_s_barrier();

    bf16x8 af[4][2], bf[2][2];
#pragma unroll
    for (int f = 0; f < 4; ++f) {
      const int row = wm * 64 + f * 16 + l16;
#pragma unroll
      for (int kk = 0; kk < 2; ++kk)
        af[f][kk] = *(const bf16x8*)(As + row * 64 +
                                     (((kk << 5) | (quad << 3)) ^ kx));
    }
#pragma unroll
    for (int u = 0; u < 2; ++u) {
      const int row = wn * 64 + u * 16 + l16;
#pragma unroll
      for (int kk = 0; kk < 2; ++kk)
        bf[u][kk] = *(const bf16x8*)(Bs + row * 64 +
                                     (((kk << 5) | (quad << 3)) ^ kx));
    }
    stageA(st, sb);
    __builtin_amdgcn_s_barrier();
    asm volatile("s_waitcnt lgkmcnt(0)" ::: "memory");
    __builtin_amdgcn_sched_barrier(0);
    __builtin_amdgcn_s_setprio(1);
#pragma unroll
    for (int f = 0; f < 4; ++f)
#pragma unroll
      for (int u = 0; u < 2; ++u)
#pragma unroll
        for (int kk = 0; kk < 2; ++kk)
          acc[f][u] = __builtin_amdgcn_mfma_f32_16x16x32_bf16(
              af[f][kk], bf[u][kk], acc[f][u], 0, 0, 0);
    __builtin_amdgcn_s_setprio(0);
    __builtin_amdgcn_s_barrier();

#pragma unroll
    for (int u = 0; u < 2; ++u) {
      const int row = wn * 64 + 32 + u * 16 + l16;
#pragma unroll
      for (int kk = 0; kk < 2; ++kk)
        bf[u][kk] = *(const bf16x8*)(Bs + row * 64 +
                                     (((kk << 5) | (quad << 3)) ^ kx));
    }
    stageB(st, sb);
    __builtin_amdgcn_s_barrier();
    asm volatile("s_waitcnt lgkmcnt(0)" ::: "memory");
    __builtin_amdgcn_sched_barrier(0);
    __builtin_amdgcn_s_setprio(1);
#pragma unroll
    for (int f = 0; f < 4; ++f)
#pragma unroll
      for (int u = 0; u < 2; ++u)
#pragma unroll
        for (int kk = 0; kk < 2; ++kk)
          acc[f][2 + u] = __builtin_amdgcn_mfma_f32_16x16x32_bf16(
              af[f][kk], bf[u][kk], acc[f][2 + u], 0, 0, 0);
    __builtin_amdgcn_s_setprio(0);

    buf = (buf == 2) ? 0 : buf + 1;
    sb = (sb == 2) ? 0 : sb + 1;
  }

  asm volatile("s_waitcnt vmcnt(0)" ::: "memory");

#pragma unroll
  for (int j = 0; j < 4; ++j) {
    const int n = n0 + wn * 64 + j * 16 + l16;
    const float bv = bias[n];
#pragma unroll
    for (int f = 0; f < 4; ++f) {
      const int mb = m0 + wm * 64 + f * 16 + quad * 4;
#pragma unroll
      for (int r = 0; r < 4; ++r)
        C[(size_t)(mb + r) * N + n] = acc[f][j][r] + bv;
    }
  }
}

// ---------------------------------------------------------------------------
// Kernel 4: causal flash attention v6 — double-buffered 64-col K/V tiles,
// ONE barrier per iter, post-barrier prefetch. 512-thread blocks (8 waves x
// 16 q-rows), 128-row Q tile, grid (16,32), 2 blocks/CU (80 KiB LDS).
// Complementary pairing for causal balance. Q pre-scaled. No-max softmax;
// ones-MFMA row sums; P wave-private (zero P barriers).
// ---------------------------------------------------------------------------
__global__ __launch_bounds__(512, 4) void attn_kernel(
    const short* __restrict__ qkv, const short* __restrict__ vT,
    short* __restrict__ obuf) {
  __shared__ __align__(16) short Ks[2 * 8192];  // 2 bufs x 16 chunks x 1KiB
  __shared__ __align__(16) short Vs[2 * 8192];
  __shared__ __align__(16) short Ps[8192];      // 8 waves x 2 chunks (private)
  const int tid = threadIdx.x;
  const int wave = tid >> 6, lane = tid & 63;
  const int quad = lane >> 4, l16 = lane & 15;
  const int bh = blockIdx.y, b = bh >> 4, h = bh & 15;
  const int px = blockIdx.x;
  const int p = (blockIdx.y & 16) ? (15 - px) : px;
  const int q0 = p * 128;
  const int nkt = 2 * (p + 1);  // # of 64-col K tiles (causal)

  const short* qbase = qkv + (size_t)b * 2048 * 6144 + h * 128;
  const short* kbase = qkv + (size_t)b * 2048 * 6144 + 2048 + h * 128;
  const short* vtbase = vT + (size_t)bh * 128 * 2048;
  short* obase = obuf + (size_t)b * 2048 * 2048 + h * 128;

  const int srow = lane >> 2;        // staging: row within 16-row chunk
  const int scol = (lane & 3) * 8;   // staging: col offset within 32-col chunk

  // ones B-fragment for row-sum MFMA (bf16 1.0 = 0x3F80)
  bf16x8 ones;
#pragma unroll
  for (int j = 0; j < 8; ++j) ones[j] = (short)0x3F80;

  // Q fragments resident: wave owns 16 q-rows, 4 d-chunks of 32
  bf16x8 qf[4];
#pragma unroll
  for (int kk = 0; kk < 4; ++kk)
    qf[kk] = *(const bf16x8*)(
        qbase + (size_t)(q0 + wave * 16 + l16) * 6144 + kk * 32 + quad * 8);

  f32x4 acco[8] = {};
  f32x4 accl = {};  // row-sum accumulator

  auto stage = [&](int buf, int kt) {
    const int k0 = kt * 64;
#pragma unroll
    for (int it = 0; it < 2; ++it) {
      int c = wave * 2 + it;
      gload_lds16(
          kbase + (size_t)(k0 + (c & 3) * 16 + srow) * 6144 + (c >> 2) * 32 +
              scol,
          (const char*)Ks + buf * 16384 + c * 1024);
    }
#pragma unroll
    for (int it = 0; it < 2; ++it) {
      int c = wave * 2 + it;
      gload_lds16(
          vtbase + (size_t)((c & 7) * 16 + srow) * 2048 + k0 + (c >> 3) * 32 +
              scol,
          (const char*)Vs + buf * 16384 + c * 1024);
    }
  };

  stage(0, 0);

  for (int kt = 0; kt < nkt; ++kt) {
    const int buf = kt & 1;
    __syncthreads();  // drains staging of buf; guards other-buf reuse
    if (kt + 1 < nkt) stage(1 - buf, kt + 1);  // post-barrier prefetch
    const short* KsB = Ks + buf * 8192;
    const short* VsB = Vs + buf * 8192;

    // ---- S = Q K^T (wave: its 16 q-rows x 64 keys; scale pre-folded) ----
    f32x4 accs[4] = {};
#pragma unroll
    for (int kk = 0; kk < 4; ++kk) {
      bf16x8 bfg[4];
#pragma unroll
      for (int tn = 0; tn < 4; ++tn)
        bfg[tn] = *(const bf16x8*)(KsB + (kk * 4 + tn) * 512 + l16 * 32 +
                                   quad * 8);
#pragma unroll
      for (int tn = 0; tn < 4; ++tn)
        accs[tn] = __builtin_amdgcn_mfma_f32_16x16x32_bf16(
            qf[kk], bfg[tn], accs[tn], 0, 0, 0);
    }

    // ---- causal mask (last two tiles straddle the diagonal) + exp2 ----
    if (kt >= nkt - 2) {
      const int k0 = kt * 64;
#pragma unroll
      for (int tn = 0; tn < 4; ++tn)
#pragma unroll
        for (int r = 0; r < 4; ++r) {
          int grow = q0 + wave * 16 + quad * 4 + r;
          int gcol = k0 + tn * 16 + l16;
          if (gcol > grow) accs[tn][r] = -1e30f;
        }
    }
#pragma unroll
    for (int tn = 0; tn < 4; ++tn)
#pragma unroll
      for (int r = 0; r < 4; ++r) accs[tn][r] = exp2f(accs[tn][r]);

    // ---- write P~ A-fragment-linear into wave-private Ps (no barrier) ----
#pragma unroll
    for (int r = 0; r < 4; ++r)
#pragma unroll
      for (int tn = 0; tn < 4; ++tn)
        Ps[wave * 1024 + (tn >> 1) * 512 + (quad * 4 + r) * 32 +
           (tn & 1) * 16 + l16] = f2bf(accs[tn][r]);

    // ---- O += P~ V; row-sum += P~ @ ones ----
#pragma unroll
    for (int kk2 = 0; kk2 < 2; ++kk2) {
      bf16x8 av = *(const bf16x8*)(Ps + wave * 1024 + kk2 * 512 + l16 * 32 +
                                   quad * 8);
      accl = __builtin_amdgcn_mfma_f32_16x16x32_bf16(av, ones, accl, 0, 0, 0);
      bf16x8 bfg[8];
#pragma unroll
      for (int tn = 0; tn < 8; ++tn)
        bfg[tn] = *(const bf16x8*)(VsB + (kk2 * 8 + tn) * 512 + l16 * 32 +
                                   quad * 8);
#pragma unroll
      for (int tn = 0; tn < 8; ++tn)
        acco[tn] = __builtin_amdgcn_mfma_f32_16x16x32_bf16(
            av, bfg[tn], acco[tn], 0, 0, 0);
    }
  }

  // ---- epilogue: O /= rowsum, store bf16 to (b, s, h*128+d) ----
  float inv[4];
#pragma unroll
  for (int r = 0; r < 4; ++r) inv[r] = 1.f / accl[r];
#pragma unroll
  for (int r = 0; r < 4; ++r) {
    int row = q0 + wave * 16 + quad * 4 + r;
#pragma unroll
    for (int tn = 0; tn < 8; ++tn)
      obase[(size_t)row * 2048 + tn * 16 + l16] = f2bf(acco[tn][r] * inv[r]);
  }
}

// ---------------------------------------------------------------------------
extern "C" void kernel_launch(void* const* d_in, const int* in_sizes, int n_in,
                              void* d_out, int out_size, void* d_ws,
                              size_t ws_size, hipStream_t stream) {
  (void)in_sizes; (void)n_in; (void)out_size; (void)ws_size;
  const float* x    = (const float*)d_in[0];
  const float* Wqkv = (const float*)d_in[1];
  const float* bqkv = (const float*)d_in[2];
  const float* Wout = (const float*)d_in[3];
  const float* bout = (const float*)d_in[4];
  float* out = (float*)d_out;

  char* ws = (char*)d_ws;
  short* xb    = (short*)(ws);                    // 16,777,216 B
  short* wqkvT = (short*)(ws + 16777216);         // 25,165,824 B
  short* woutT = (short*)(ws + 41943040);         //  8,388,608 B
  short* qkv   = (short*)(ws + 50331648);         // 50,331,648 B (V part unused)
  short* vTb   = (short*)(ws + 100663296);        // 16,777,216 B
  short* obuf  = (short*)(ws + 117440512);        // 16,777,216 B -> 128 MiB total

  // 1) casts / transposes
  cast_f32_bf16<<<4096, 256, 0, stream>>>(x, xb, 1048576);
  transpose_cast_w<<<dim3(64, 192), 256, 0, stream>>>(Wqkv, wqkvT, 2048, 6144);
  transpose_cast_w<<<dim3(64, 64), 256, 0, stream>>>(Wout, woutT, 2048, 2048);

  // 2) qkv = x @ W_qkv + b_qkv; Q cols pre-scaled, V cols -> vT (coalesced)
  //    grid 16x16 = 256 blocks (256x384 tiles) = exactly 1 block/CU
  gemm_qkv<<<dim3(16, 16), 512, 0, stream>>>(
      xb, wqkvT, qkv, bqkv, vTb, 4096, 6144, 2048);

  // 3) attention: 512 blocks x 512 threads, 2 blocks/CU, dbuf K-loop
  attn_kernel<<<dim3(16, 32), 512, 0, stream>>>(qkv, vTb, obuf);

  // 4) y = O @ W_out + b_out   (M=4096, N=2048, K=2048) -> fp32
  gemm_out<<<dim3(16, 16), 512, 0, stream>>>(
      obuf, woutT, out, bout, 4096, 2048, 2048);
}

// Round 5
// 363.866 us; speedup vs baseline: 1.6653x; 1.6653x over previous
//
#include <hip/hip_runtime.h>
#include <stdint.h>
#include <stddef.h>

// ---------------------------------------------------------------------------
// TinySelfAttention on MI355X (gfx950), bf16 MFMA pipeline:
//   1) cast x -> bf16
//   2) transpose+cast W_qkv, W_out -> bf16 B^T form
//   3) GEMM 256x128 (verified round-1/2 pipeline): qkv = x @ W_qkv + b_qkv
//      - BK=64, 3-deep LDS pipeline, counted vmcnt(6), XOR-swizzled LDS,
//        setprio, raw s_barrier. Q pre-scaled; V -> per-head V^T.
//   4) flash attention v8: 512-thread blocks (8 waves x 16 q-rows), 128-row
//      Q tile, 32-col K/V tiles, 3-DEEP staging pipeline with counted
//      vmcnt(2) (never 0) + raw s_barrier (1/iter), wave-private P,
//      no-max softmax, ones-MFMA row sums. 56 KiB LDS -> 2 blocks/CU.
//   5) GEMM 256x128: y = O @ W_out + b_out (fp32 out)
// ---------------------------------------------------------------------------

typedef __attribute__((ext_vector_type(8))) short bf16x8;   // 8 x bf16 = 4 VGPRs
typedef __attribute__((ext_vector_type(4))) float f32x4;    // MFMA accumulator

#define SOFT_SCALE 0.12751743075419806f  // (1/sqrt(128)) * log2(e)

__device__ __forceinline__ short f2bf(float f) {
  union { float f; unsigned u; } v; v.f = f;
  unsigned u = v.u + 0x7fffu + ((v.u >> 16) & 1u);  // RNE
  return (short)(u >> 16);
}

__device__ __forceinline__ void gload_lds16(const void* g, const void* l) {
  // async global->LDS, 16B per lane; LDS dest = wave-uniform base + lane*16
  __builtin_amdgcn_global_load_lds(
      (__attribute__((address_space(1))) void*)(uintptr_t)g,
      (__attribute__((address_space(3))) void*)(uintptr_t)l,
      16, 0, 0);
}

// ---------------------------------------------------------------------------
// Kernel 1: fp32 -> bf16 cast, 8 elems/thread
// ---------------------------------------------------------------------------
__global__ __launch_bounds__(256) void cast_f32_bf16(
    const float* __restrict__ in, short* __restrict__ out, int n8) {
  int i = blockIdx.x * 256 + threadIdx.x;
  if (i >= n8) return;
  float4 a = ((const float4*)in)[i * 2];
  float4 b = ((const float4*)in)[i * 2 + 1];
  bf16x8 o;
  o[0] = f2bf(a.x); o[1] = f2bf(a.y); o[2] = f2bf(a.z); o[3] = f2bf(a.w);
  o[4] = f2bf(b.x); o[5] = f2bf(b.y); o[6] = f2bf(b.z); o[7] = f2bf(b.w);
  ((bf16x8*)out)[i] = o;
}

// ---------------------------------------------------------------------------
// Kernel 2: W [K][N] fp32 -> WT [N][K] bf16, 32x32 tiles
// ---------------------------------------------------------------------------
__global__ __launch_bounds__(256) void transpose_cast_w(
    const float* __restrict__ W, short* __restrict__ WT, int K, int N) {
  __shared__ short t[32][33];
  int k0 = blockIdx.x * 32, n0 = blockIdx.y * 32;
  int r = threadIdx.x >> 3;
  int c = (threadIdx.x & 7) * 4;
  float4 v = *(const float4*)(W + (size_t)(k0 + r) * N + n0 + c);
  t[r][c + 0] = f2bf(v.x); t[r][c + 1] = f2bf(v.y);
  t[r][c + 2] = f2bf(v.z); t[r][c + 3] = f2bf(v.w);
  __syncthreads();
  short4 o;
  o.x = t[c + 0][r]; o.y = t[c + 1][r]; o.z = t[c + 2][r]; o.w = t[c + 3][r];
  *(short4*)(WT + (size_t)(n0 + r) * K + k0 + c) = o;
}

// ---------------------------------------------------------------------------
// Kernel 3: GEMM v3  C[M][N] = A[M][K] @ BT[N][K]^T + bias
// 256x128 tile, BK=64, 512 threads = 8 waves as 4(m) x 2(n), per-wave 64x64.
// 3-deep LDS pipeline, counted vmcnt(6), 2 phases/K-tile, XOR-swizzled LDS,
// raw s_barrier (no compiler vmcnt(0) drain), setprio around MFMA clusters.
// (Verified passing in rounds 1-2 at ~122 us.)
// ---------------------------------------------------------------------------
template <int BF16OUT, int VTRANS, int QSCALE>
__global__ __launch_bounds__(512, 2) void gemm256(
    const short* __restrict__ A, const short* __restrict__ BT,
    void* __restrict__ Cv, const float* __restrict__ bias,
    short* __restrict__ vTout, int M, int N, int K) {
  (void)M;
  __shared__ __align__(16) short SH[73728];  // 147456 B = 3 x 49152
  const int tid = threadIdx.x;
  const int wave = tid >> 6, lane = tid & 63;
  const int quad = lane >> 4, l16 = lane & 15;
  const int wm = wave >> 1, wn = wave & 1;   // 4 x 2 wave grid
  const int kx = (l16 & 7) << 3;             // read-side swizzle key (shorts)

  // XCD-aware bijective swizzle (nwg % 8 == 0 at both call sites)
  const int gx = gridDim.x;
  int bid = blockIdx.y * gx + blockIdx.x;
  const int nwg = gx * gridDim.y;
  bid = (bid & 7) * (nwg >> 3) + (bid >> 3);
  const int m0 = (bid % gx) * 256, n0 = (bid / gx) * 128;

  // staging: chunk = 8 rows x 64 cols = 1 KiB, one gload_lds16 per wave.
  const int rsub = lane >> 3;                 // row within 8-row chunk
  const int csub = ((lane & 7) ^ rsub) << 3;  // pre-swizzled col (shorts)
  const short* aS[4];
  const short* bS[2];
#pragma unroll
  for (int i = 0; i < 4; ++i)
    aS[i] = A + (size_t)(m0 + (wave * 4 + i) * 8 + rsub) * K + csub;
#pragma unroll
  for (int i = 0; i < 2; ++i)
    bS[i] = BT + (size_t)(n0 + (wave * 2 + i) * 8 + rsub) * K + csub;

  auto stageA = [&](int st, int sb) {
#pragma unroll
    for (int i = 0; i < 4; ++i)
      gload_lds16(aS[i] + st * 64,
                  (const char*)SH + sb * 49152 + (wave * 4 + i) * 1024);
  };
  auto stageB = [&](int st, int sb) {
#pragma unroll
    for (int i = 0; i < 2; ++i)
      gload_lds16(bS[i] + st * 64,
                  (const char*)SH + sb * 49152 + 32768 + (wave * 2 + i) * 1024);
  };

  // prologue: tiles 0 and 1 in flight (12 loads/wave outstanding)
  stageA(0, 0); stageB(0, 0);
  stageA(1, 1); stageB(1, 1);

  f32x4 acc[4][4] = {};
  const int nT = K >> 6;
  int buf = 0, sb = 2;
  for (int t = 0; t < nT; ++t) {
    const int st = (t + 2 < nT) ? (t + 2) : (nT - 1);  // clamp: uniform vmcnt
    const short* As = (const short*)((const char*)SH + buf * 49152);
    const short* Bs = As + 16384;

    asm volatile("s_waitcnt vmcnt(6)" ::: "memory");
    __builtin_amdgcn_s_barrier();

    // ---- phase 1: ds-read A(8) + B.lo(4) | stage A(t+2) | 16 MFMA ----
    bf16x8 af[4][2], bf[2][2];
#pragma unroll
    for (int f = 0; f < 4; ++f) {
      const int row = wm * 64 + f * 16 + l16;
#pragma unroll
      for (int kk = 0; kk < 2; ++kk)
        af[f][kk] = *(const bf16x8*)(As + row * 64 +
                                     (((kk << 5) | (quad << 3)) ^ kx));
    }
#pragma unroll
    for (int u = 0; u < 2; ++u) {
      const int row = wn * 64 + u * 16 + l16;
#pragma unroll
      for (int kk = 0; kk < 2; ++kk)
        bf[u][kk] = *(const bf16x8*)(Bs + row * 64 +
                                     (((kk << 5) | (quad << 3)) ^ kx));
    }
    stageA(st, sb);
    __builtin_amdgcn_s_barrier();
    asm volatile("s_waitcnt lgkmcnt(0)" ::: "memory");
    __builtin_amdgcn_sched_barrier(0);
    __builtin_amdgcn_s_setprio(1);
#pragma unroll
    for (int f = 0; f < 4; ++f)
#pragma unroll
      for (int u = 0; u < 2; ++u)
#pragma unroll
        for (int kk = 0; kk < 2; ++kk)
          acc[f][u] = __builtin_amdgcn_mfma_f32_16x16x32_bf16(
              af[f][kk], bf[u][kk], acc[f][u], 0, 0, 0);
    __builtin_amdgcn_s_setprio(0);
    __builtin_amdgcn_s_barrier();

    // ---- phase 2: ds-read B.hi(4) | stage B(t+2) | 16 MFMA ----
#pragma unroll
    for (int u = 0; u < 2; ++u) {
      const int row = wn * 64 + 32 + u * 16 + l16;
#pragma unroll
      for (int kk = 0; kk < 2; ++kk)
        bf[u][kk] = *(const bf16x8*)(Bs + row * 64 +
                                     (((kk << 5) | (quad << 3)) ^ kx));
    }
    stageB(st, sb);
    __builtin_amdgcn_s_barrier();
    asm volatile("s_waitcnt lgkmcnt(0)" ::: "memory");
    __builtin_amdgcn_sched_barrier(0);
    __builtin_amdgcn_s_setprio(1);
#pragma unroll
    for (int f = 0; f < 4; ++f)
#pragma unroll
      for (int u = 0; u < 2; ++u)
#pragma unroll
        for (int kk = 0; kk < 2; ++kk)
          acc[f][2 + u] = __builtin_amdgcn_mfma_f32_16x16x32_bf16(
              af[f][kk], bf[u][kk], acc[f][2 + u], 0, 0, 0);
    __builtin_amdgcn_s_setprio(0);

    buf = (buf == 2) ? 0 : buf + 1;
    sb = (sb == 2) ? 0 : sb + 1;
  }

  if (VTRANS && n0 >= 4096) {
    // Drain clamped duplicate prefetches, then transpose through LDS
    // T[128 n][264 m-pad]; write vT[bh][d][s] rows (512B segments).
    asm volatile("s_waitcnt vmcnt(0)" ::: "memory");
    __builtin_amdgcn_s_barrier();
    short* T = (short*)SH;
#pragma unroll
    for (int j = 0; j < 4; ++j) {
      const int nl = wn * 64 + j * 16 + l16;
      const float bv = bias[n0 + nl];
#pragma unroll
      for (int f = 0; f < 4; ++f) {
        const int ml = wm * 64 + f * 16 + quad * 4;
        short4 o;
        o.x = f2bf(acc[f][j][0] + bv);
        o.y = f2bf(acc[f][j][1] + bv);
        o.z = f2bf(acc[f][j][2] + bv);
        o.w = f2bf(acc[f][j][3] + bv);
        *(short4*)(T + nl * 264 + ml) = o;
      }
    }
    __builtin_amdgcn_s_barrier();
    const int b = m0 >> 11, s0 = m0 & 2047, h = (n0 - 4096) >> 7;
#pragma unroll
    for (int pass = 0; pass < 8; ++pass) {
      const int row = pass * 16 + (tid >> 5);
      const int c = (tid & 31) * 8;
      bf16x8 v = *(const bf16x8*)(T + row * 264 + c);
      *(bf16x8*)(vTout + ((size_t)((b * 16 + h) * 128 + row)) * 2048 + s0 +
                 c) = v;
    }
    return;
  }

  asm volatile("s_waitcnt vmcnt(0)" ::: "memory");

#pragma unroll
  for (int j = 0; j < 4; ++j) {
    const int n = n0 + wn * 64 + j * 16 + l16;
    const float bv = bias[n];
#pragma unroll
    for (int f = 0; f < 4; ++f) {
      const int mb = m0 + wm * 64 + f * 16 + quad * 4;
#pragma unroll
      for (int r = 0; r < 4; ++r) {
        float v = acc[f][j][r] + bv;
        if (QSCALE && n < 2048) v *= SOFT_SCALE;
        if (BF16OUT)
          ((short*)Cv)[(size_t)(mb + r) * N + n] = f2bf(v);
        else
          ((float*)Cv)[(size_t)(mb + r) * N + n] = v;
      }
    }
  }
}

// ---------------------------------------------------------------------------
// Kernel 4: causal flash attention v8 — 32-col K/V tiles in a 3-DEEP
// staging pipeline: counted vmcnt(2) at each iter (never 0), raw s_barrier
// (1/iter), stage(t+2) issued post-barrier so DMA latency is covered by two
// full compute phases. 512-thread blocks (8 waves x 16 q-rows), 128-row Q
// tile, grid (16,32), 56 KiB LDS -> 2 blocks/CU. Complementary pairing for
// causal balance. Q pre-scaled. No-max softmax; ones-MFMA row sums; P
// wave-private (zero P barriers). Layouts are v6's verified ones rescaled
// to 32-col tiles (chunk = 16 rows x 32 cols = 1 KiB).
// ---------------------------------------------------------------------------
__global__ __launch_bounds__(512, 4) void attn_kernel(
    const short* __restrict__ qkv, const short* __restrict__ vT,
    short* __restrict__ obuf) {
  __shared__ __align__(16) short Ks[3 * 4096];  // 3 bufs x 8 chunks x 1KiB
  __shared__ __align__(16) short Vs[3 * 4096];
  __shared__ __align__(16) short Ps[4096];      // 8 waves x 512 (private)
  const int tid = threadIdx.x;
  const int wave = tid >> 6, lane = tid & 63;
  const int quad = lane >> 4, l16 = lane & 15;
  const int bh = blockIdx.y, b = bh >> 4, h = bh & 15;
  const int px = blockIdx.x;
  const int p = (blockIdx.y & 16) ? (15 - px) : px;
  const int q0 = p * 128;
  const int nkt = 4 * (p + 1);  // # of 32-col K tiles (causal), >= 4

  const short* qbase = qkv + (size_t)b * 2048 * 6144 + h * 128;
  const short* kbase = qkv + (size_t)b * 2048 * 6144 + 2048 + h * 128;
  const short* vtbase = vT + (size_t)bh * 128 * 2048;
  short* obase = obuf + (size_t)b * 2048 * 2048 + h * 128;

  const int srow = lane >> 2;        // staging: row within 16-row chunk
  const int scol = (lane & 3) * 8;   // staging: col offset within 32-col chunk

  // ones B-fragment for row-sum MFMA (bf16 1.0 = 0x3F80)
  bf16x8 ones;
#pragma unroll
  for (int j = 0; j < 8; ++j) ones[j] = (short)0x3F80;

  // Q fragments resident: wave owns 16 q-rows, 4 d-chunks of 32
  bf16x8 qf[4];
#pragma unroll
  for (int kk = 0; kk < 4; ++kk)
    qf[kk] = *(const bf16x8*)(
        qbase + (size_t)(q0 + wave * 16 + l16) * 6144 + kk * 32 + quad * 8);

  f32x4 acco[8] = {};
  f32x4 accl = {};  // row-sum accumulator

  // stage K/V tile kt into buffer sb: per wave 2 loads (K chunk 'wave',
  // V chunk 'wave'). K chunk c: keys (c&1)*16+srow, d (c>>1)*32+scol.
  // V chunk c: d-rows c*16+srow, s-cols k0+scol. Chunk = [16][32] row-major.
  auto stage = [&](int sb, int kt) {
    const int k0 = kt * 32;
    gload_lds16(
        kbase + (size_t)(k0 + (wave & 1) * 16 + srow) * 6144 +
            (wave >> 1) * 32 + scol,
        (const char*)Ks + sb * 8192 + wave * 1024);
    gload_lds16(
        vtbase + (size_t)(wave * 16 + srow) * 2048 + k0 + scol,
        (const char*)Vs + sb * 8192 + wave * 1024);
  };

  // prologue: tiles 0 and 1 in flight (4 loads/wave outstanding)
  stage(0, 0);
  stage(1, 1);

  int buf = 0;
  for (int kt = 0; kt < nkt; ++kt) {
    const int st = (kt + 2 < nkt) ? (kt + 2) : (nkt - 1);  // clamped tail
    // tile kt's 2 loads are the oldest; leave tile kt+1's 2 in flight.
    asm volatile("s_waitcnt vmcnt(2)" ::: "memory");
    __builtin_amdgcn_s_barrier();
    const int sbn = (buf >= 1) ? buf - 1 : 2;  // (buf+2)%3
    stage(sbn, st);  // post-barrier prefetch of tile kt+2
    const short* KsB = Ks + buf * 4096;
    const short* VsB = Vs + buf * 4096;

    // ---- S = Q K^T (wave: its 16 q-rows x 32 keys; scale pre-folded) ----
    f32x4 accs[2] = {};
#pragma unroll
    for (int kk = 0; kk < 4; ++kk) {
      bf16x8 bfg[2];
#pragma unroll
      for (int tn = 0; tn < 2; ++tn)
        bfg[tn] = *(const bf16x8*)(KsB + (kk * 2 + tn) * 512 + l16 * 32 +
                                   quad * 8);
#pragma unroll
      for (int tn = 0; tn < 2; ++tn)
        accs[tn] = __builtin_amdgcn_mfma_f32_16x16x32_bf16(
            qf[kk], bfg[tn], accs[tn], 0, 0, 0);
    }

    // ---- causal mask (last four tiles straddle the diagonal) + exp2 ----
    if (kt >= nkt - 4) {
      const int k0 = kt * 32;
#pragma unroll
      for (int tn = 0; tn < 2; ++tn)
#pragma unroll
        for (int r = 0; r < 4; ++r) {
          int grow = q0 + wave * 16 + quad * 4 + r;
          int gcol = k0 + tn * 16 + l16;
          if (gcol > grow) accs[tn][r] = -1e30f;
        }
    }
#pragma unroll
    for (int tn = 0; tn < 2; ++tn)
#pragma unroll
      for (int r = 0; r < 4; ++r) accs[tn][r] = exp2f(accs[tn][r]);

    // ---- write P~ (A-frag row-major [16][32]) into wave-private Ps ----
#pragma unroll
    for (int r = 0; r < 4; ++r)
#pragma unroll
      for (int tn = 0; tn < 2; ++tn)
        Ps[wave * 512 + (quad * 4 + r) * 32 + tn * 16 + l16] =
            f2bf(accs[tn][r]);

    // ---- O += P~ V; row-sum += P~ @ ones ----
    bf16x8 av = *(const bf16x8*)(Ps + wave * 512 + l16 * 32 + quad * 8);
    accl = __builtin_amdgcn_mfma_f32_16x16x32_bf16(av, ones, accl, 0, 0, 0);
    bf16x8 bfg[8];
#pragma unroll
    for (int tn = 0; tn < 8; ++tn)
      bfg[tn] = *(const bf16x8*)(VsB + tn * 512 + l16 * 32 + quad * 8);
#pragma unroll
    for (int tn = 0; tn < 8; ++tn)
      acco[tn] = __builtin_amdgcn_mfma_f32_16x16x32_bf16(
          av, bfg[tn], acco[tn], 0, 0, 0);

    buf = (buf == 2) ? 0 : buf + 1;
  }

  // drain clamped duplicate prefetch DMAs before exit
  asm volatile("s_waitcnt vmcnt(0)" ::: "memory");

  // ---- epilogue: O /= rowsum, store bf16 to (b, s, h*128+d) ----
  float inv[4];
#pragma unroll
  for (int r = 0; r < 4; ++r) inv[r] = 1.f / accl[r];
#pragma unroll
  for (int r = 0; r < 4; ++r) {
    int row = q0 + wave * 16 + quad * 4 + r;
#pragma unroll
    for (int tn = 0; tn < 8; ++tn)
      obase[(size_t)row * 2048 + tn * 16 + l16] = f2bf(acco[tn][r] * inv[r]);
  }
}

// ---------------------------------------------------------------------------
extern "C" void kernel_launch(void* const* d_in, const int* in_sizes, int n_in,
                              void* d_out, int out_size, void* d_ws,
                              size_t ws_size, hipStream_t stream) {
  (void)in_sizes; (void)n_in; (void)out_size; (void)ws_size;
  const float* x    = (const float*)d_in[0];
  const float* Wqkv = (const float*)d_in[1];
  const float* bqkv = (const float*)d_in[2];
  const float* Wout = (const float*)d_in[3];
  const float* bout = (const float*)d_in[4];
  float* out = (float*)d_out;

  char* ws = (char*)d_ws;
  short* xb    = (short*)(ws);                    // 16,777,216 B
  short* wqkvT = (short*)(ws + 16777216);         // 25,165,824 B
  short* woutT = (short*)(ws + 41943040);         //  8,388,608 B
  short* qkv   = (short*)(ws + 50331648);         // 50,331,648 B (V part unused)
  short* vTb   = (short*)(ws + 100663296);        // 16,777,216 B
  short* obuf  = (short*)(ws + 117440512);        // 16,777,216 B -> 128 MiB total

  // 1) casts / transposes
  cast_f32_bf16<<<4096, 256, 0, stream>>>(x, xb, 1048576);
  transpose_cast_w<<<dim3(64, 192), 256, 0, stream>>>(Wqkv, wqkvT, 2048, 6144);
  transpose_cast_w<<<dim3(64, 64), 256, 0, stream>>>(Wout, woutT, 2048, 2048);

  // 2) qkv = x @ W_qkv + b_qkv; Q cols pre-scaled, V cols -> vT (coalesced)
  //    grid 16x48 = 768 blocks (256x128 tiles) = 3 full CU-rounds
  gemm256<1, 1, 1><<<dim3(16, 48), 512, 0, stream>>>(
      xb, wqkvT, (void*)qkv, bqkv, vTb, 4096, 6144, 2048);

  // 3) attention: 512 blocks x 512 threads, 2 blocks/CU, 3-deep K/V pipeline
  attn_kernel<<<dim3(16, 32), 512, 0, stream>>>(qkv, vTb, obuf);

  // 4) y = O @ W_out + b_out   (M=4096, N=2048, K=2048) -> fp32
  gemm256<0, 0, 0><<<dim3(16, 16), 512, 0, stream>>>(
      obuf, woutT, (void*)out, bout, nullptr, 4096, 2048, 2048);
}

// Round 7
// 363.297 us; speedup vs baseline: 1.6679x; 1.0016x over previous
//
#include <hip/hip_runtime.h>
#include <stdint.h>
#include <stddef.h>

// ---------------------------------------------------------------------------
// TinySelfAttention on MI355X (gfx950), bf16 MFMA pipeline:
//   1) cast x -> bf16
//   2) transpose+cast W_qkv, W_out -> bf16 B^T form
//   3) GEMM 256x128 (verified round-1/2 pipeline): qkv = x @ W_qkv + b_qkv
//      - BK=64, 3-deep LDS pipeline, counted vmcnt(6), XOR-swizzled LDS,
//        setprio, raw s_barrier. Q pre-scaled; V -> per-head V^T.
//   4) flash attention v9: 512-thread blocks (8 waves x 16 q-rows), 128-row
//      Q tile, 32-col K/V tiles, 4-DEEP staging pipeline with counted
//      vmcnt(4) (never 0) + raw s_barrier (1/iter), STREAMED fragment reads
//      (low VGPR pressure -> no spill at 4 waves/SIMD), wave-private P,
//      no-max softmax, ones-MFMA row sums. 72 KiB LDS -> 2 blocks/CU.
//   5) GEMM 256x128: y = O @ W_out + b_out (fp32 out)
// ---------------------------------------------------------------------------

typedef __attribute__((ext_vector_type(8))) short bf16x8;   // 8 x bf16 = 4 VGPRs
typedef __attribute__((ext_vector_type(4))) float f32x4;    // MFMA accumulator

#define SOFT_SCALE 0.12751743075419806f  // (1/sqrt(128)) * log2(e)

__device__ __forceinline__ short f2bf(float f) {
  union { float f; unsigned u; } v; v.f = f;
  unsigned u = v.u + 0x7fffu + ((v.u >> 16) & 1u);  // RNE
  return (short)(u >> 16);
}

__device__ __forceinline__ void gload_lds16(const void* g, const void* l) {
  // async global->LDS, 16B per lane; LDS dest = wave-uniform base + lane*16
  __builtin_amdgcn_global_load_lds(
      (__attribute__((address_space(1))) void*)(uintptr_t)g,
      (__attribute__((address_space(3))) void*)(uintptr_t)l,
      16, 0, 0);
}

// ---------------------------------------------------------------------------
// Kernel 1: fp32 -> bf16 cast, 8 elems/thread
// ---------------------------------------------------------------------------
__global__ __launch_bounds__(256) void cast_f32_bf16(
    const float* __restrict__ in, short* __restrict__ out, int n8) {
  int i = blockIdx.x * 256 + threadIdx.x;
  if (i >= n8) return;
  float4 a = ((const float4*)in)[i * 2];
  float4 b = ((const float4*)in)[i * 2 + 1];
  bf16x8 o;
  o[0] = f2bf(a.x); o[1] = f2bf(a.y); o[2] = f2bf(a.z); o[3] = f2bf(a.w);
  o[4] = f2bf(b.x); o[5] = f2bf(b.y); o[6] = f2bf(b.z); o[7] = f2bf(b.w);
  ((bf16x8*)out)[i] = o;
}

// ---------------------------------------------------------------------------
// Kernel 2: W [K][N] fp32 -> WT [N][K] bf16, 32x32 tiles
// ---------------------------------------------------------------------------
__global__ __launch_bounds__(256) void transpose_cast_w(
    const float* __restrict__ W, short* __restrict__ WT, int K, int N) {
  __shared__ short t[32][33];
  int k0 = blockIdx.x * 32, n0 = blockIdx.y * 32;
  int r = threadIdx.x >> 3;
  int c = (threadIdx.x & 7) * 4;
  float4 v = *(const float4*)(W + (size_t)(k0 + r) * N + n0 + c);
  t[r][c + 0] = f2bf(v.x); t[r][c + 1] = f2bf(v.y);
  t[r][c + 2] = f2bf(v.z); t[r][c + 3] = f2bf(v.w);
  __syncthreads();
  short4 o;
  o.x = t[c + 0][r]; o.y = t[c + 1][r]; o.z = t[c + 2][r]; o.w = t[c + 3][r];
  *(short4*)(WT + (size_t)(n0 + r) * K + k0 + c) = o;
}

// ---------------------------------------------------------------------------
// Kernel 3: GEMM v3  C[M][N] = A[M][K] @ BT[N][K]^T + bias
// 256x128 tile, BK=64, 512 threads = 8 waves as 4(m) x 2(n), per-wave 64x64.
// 3-deep LDS pipeline, counted vmcnt(6), 2 phases/K-tile, XOR-swizzled LDS,
// raw s_barrier (no compiler vmcnt(0) drain), setprio around MFMA clusters.
// (Verified passing in rounds 1-2-5 at ~122-126 us.)
// ---------------------------------------------------------------------------
template <int BF16OUT, int VTRANS, int QSCALE>
__global__ __launch_bounds__(512, 2) void gemm256(
    const short* __restrict__ A, const short* __restrict__ BT,
    void* __restrict__ Cv, const float* __restrict__ bias,
    short* __restrict__ vTout, int M, int N, int K) {
  (void)M;
  __shared__ __align__(16) short SH[73728];  // 147456 B = 3 x 49152
  const int tid = threadIdx.x;
  const int wave = tid >> 6, lane = tid & 63;
  const int quad = lane >> 4, l16 = lane & 15;
  const int wm = wave >> 1, wn = wave & 1;   // 4 x 2 wave grid
  const int kx = (l16 & 7) << 3;             // read-side swizzle key (shorts)

  // XCD-aware bijective swizzle (nwg % 8 == 0 at both call sites)
  const int gx = gridDim.x;
  int bid = blockIdx.y * gx + blockIdx.x;
  const int nwg = gx * gridDim.y;
  bid = (bid & 7) * (nwg >> 3) + (bid >> 3);
  const int m0 = (bid % gx) * 256, n0 = (bid / gx) * 128;

  // staging: chunk = 8 rows x 64 cols = 1 KiB, one gload_lds16 per wave.
  const int rsub = lane >> 3;                 // row within 8-row chunk
  const int csub = ((lane & 7) ^ rsub) << 3;  // pre-swizzled col (shorts)
  const short* aS[4];
  const short* bS[2];
#pragma unroll
  for (int i = 0; i < 4; ++i)
    aS[i] = A + (size_t)(m0 + (wave * 4 + i) * 8 + rsub) * K + csub;
#pragma unroll
  for (int i = 0; i < 2; ++i)
    bS[i] = BT + (size_t)(n0 + (wave * 2 + i) * 8 + rsub) * K + csub;

  auto stageA = [&](int st, int sb) {
#pragma unroll
    for (int i = 0; i < 4; ++i)
      gload_lds16(aS[i] + st * 64,
                  (const char*)SH + sb * 49152 + (wave * 4 + i) * 1024);
  };
  auto stageB = [&](int st, int sb) {
#pragma unroll
    for (int i = 0; i < 2; ++i)
      gload_lds16(bS[i] + st * 64,
                  (const char*)SH + sb * 49152 + 32768 + (wave * 2 + i) * 1024);
  };

  // prologue: tiles 0 and 1 in flight (12 loads/wave outstanding)
  stageA(0, 0); stageB(0, 0);
  stageA(1, 1); stageB(1, 1);

  f32x4 acc[4][4] = {};
  const int nT = K >> 6;
  int buf = 0, sb = 2;
  for (int t = 0; t < nT; ++t) {
    const int st = (t + 2 < nT) ? (t + 2) : (nT - 1);  // clamp: uniform vmcnt
    const short* As = (const short*)((const char*)SH + buf * 49152);
    const short* Bs = As + 16384;

    asm volatile("s_waitcnt vmcnt(6)" ::: "memory");
    __builtin_amdgcn_s_barrier();

    // ---- phase 1: ds-read A(8) + B.lo(4) | stage A(t+2) | 16 MFMA ----
    bf16x8 af[4][2], bf[2][2];
#pragma unroll
    for (int f = 0; f < 4; ++f) {
      const int row = wm * 64 + f * 16 + l16;
#pragma unroll
      for (int kk = 0; kk < 2; ++kk)
        af[f][kk] = *(const bf16x8*)(As + row * 64 +
                                     (((kk << 5) | (quad << 3)) ^ kx));
    }
#pragma unroll
    for (int u = 0; u < 2; ++u) {
      const int row = wn * 64 + u * 16 + l16;
#pragma unroll
      for (int kk = 0; kk < 2; ++kk)
        bf[u][kk] = *(const bf16x8*)(Bs + row * 64 +
                                     (((kk << 5) | (quad << 3)) ^ kx));
    }
    stageA(st, sb);
    __builtin_amdgcn_s_barrier();
    asm volatile("s_waitcnt lgkmcnt(0)" ::: "memory");
    __builtin_amdgcn_sched_barrier(0);
    __builtin_amdgcn_s_setprio(1);
#pragma unroll
    for (int f = 0; f < 4; ++f)
#pragma unroll
      for (int u = 0; u < 2; ++u)
#pragma unroll
        for (int kk = 0; kk < 2; ++kk)
          acc[f][u] = __builtin_amdgcn_mfma_f32_16x16x32_bf16(
              af[f][kk], bf[u][kk], acc[f][u], 0, 0, 0);
    __builtin_amdgcn_s_setprio(0);
    __builtin_amdgcn_s_barrier();

    // ---- phase 2: ds-read B.hi(4) | stage B(t+2) | 16 MFMA ----
#pragma unroll
    for (int u = 0; u < 2; ++u) {
      const int row = wn * 64 + 32 + u * 16 + l16;
#pragma unroll
      for (int kk = 0; kk < 2; ++kk)
        bf[u][kk] = *(const bf16x8*)(Bs + row * 64 +
                                     (((kk << 5) | (quad << 3)) ^ kx));
    }
    stageB(st, sb);
    __builtin_amdgcn_s_barrier();
    asm volatile("s_waitcnt lgkmcnt(0)" ::: "memory");
    __builtin_amdgcn_sched_barrier(0);
    __builtin_amdgcn_s_setprio(1);
#pragma unroll
    for (int f = 0; f < 4; ++f)
#pragma unroll
      for (int u = 0; u < 2; ++u)
#pragma unroll
        for (int kk = 0; kk < 2; ++kk)
          acc[f][2 + u] = __builtin_amdgcn_mfma_f32_16x16x32_bf16(
              af[f][kk], bf[u][kk], acc[f][2 + u], 0, 0, 0);
    __builtin_amdgcn_s_setprio(0);

    buf = (buf == 2) ? 0 : buf + 1;
    sb = (sb == 2) ? 0 : sb + 1;
  }

  if (VTRANS && n0 >= 4096) {
    // Drain clamped duplicate prefetches, then transpose through LDS
    // T[128 n][264 m-pad]; write vT[bh][d][s] rows (512B segments).
    asm volatile("s_waitcnt vmcnt(0)" ::: "memory");
    __builtin_amdgcn_s_barrier();
    short* T = (short*)SH;
#pragma unroll
    for (int j = 0; j < 4; ++j) {
      const int nl = wn * 64 + j * 16 + l16;
      const float bv = bias[n0 + nl];
#pragma unroll
      for (int f = 0; f < 4; ++f) {
        const int ml = wm * 64 + f * 16 + quad * 4;
        short4 o;
        o.x = f2bf(acc[f][j][0] + bv);
        o.y = f2bf(acc[f][j][1] + bv);
        o.z = f2bf(acc[f][j][2] + bv);
        o.w = f2bf(acc[f][j][3] + bv);
        *(short4*)(T + nl * 264 + ml) = o;
      }
    }
    __builtin_amdgcn_s_barrier();
    const int b = m0 >> 11, s0 = m0 & 2047, h = (n0 - 4096) >> 7;
#pragma unroll
    for (int pass = 0; pass < 8; ++pass) {
      const int row = pass * 16 + (tid >> 5);
      const int c = (tid & 31) * 8;
      bf16x8 v = *(const bf16x8*)(T + row * 264 + c);
      *(bf16x8*)(vTout + ((size_t)((b * 16 + h) * 128 + row)) * 2048 + s0 +
                 c) = v;
    }
    return;
  }

  asm volatile("s_waitcnt vmcnt(0)" ::: "memory");

#pragma unroll
  for (int j = 0; j < 4; ++j) {
    const int n = n0 + wn * 64 + j * 16 + l16;
    const float bv = bias[n];
#pragma unroll
    for (int f = 0; f < 4; ++f) {
      const int mb = m0 + wm * 64 + f * 16 + quad * 4;
#pragma unroll
      for (int r = 0; r < 4; ++r) {
        float v = acc[f][j][r] + bv;
        if (QSCALE && n < 2048) v *= SOFT_SCALE;
        if (BF16OUT)
          ((short*)Cv)[(size_t)(mb + r) * N + n] = f2bf(v);
        else
          ((float*)Cv)[(size_t)(mb + r) * N + n] = v;
      }
    }
  }
}

// ---------------------------------------------------------------------------
// Kernel 4: causal flash attention v9 — 32-col K/V tiles in a 4-DEEP
// staging pipeline: counted vmcnt(4) at each iter (never 0; two full
// iterations of DMA cover), raw s_barrier (1/iter), STREAMED fragment reads
// so peak VGPR stays ~110 (no spill at the 4-waves/SIMD launch bound).
// 512-thread blocks (8 waves x 16 q-rows), 128-row Q tile, grid (16,32),
// 72 KiB LDS -> 2 blocks/CU. Complementary pairing for causal balance.
// Q pre-scaled. No-max softmax; ones-MFMA row sums; P wave-private.
// Layouts identical to v8 (verified passing in round 5).
// ---------------------------------------------------------------------------
__global__ __launch_bounds__(512, 4) void attn_kernel(
    const short* __restrict__ qkv, const short* __restrict__ vT,
    short* __restrict__ obuf) {
  __shared__ __align__(16) short Ks[4 * 4096];  // 4 bufs x 8 chunks x 1KiB
  __shared__ __align__(16) short Vs[4 * 4096];
  __shared__ __align__(16) short Ps[4096];      // 8 waves x 512 (private)
  const int tid = threadIdx.x;
  const int wave = tid >> 6, lane = tid & 63;
  const int quad = lane >> 4, l16 = lane & 15;
  const int bh = blockIdx.y, b = bh >> 4, h = bh & 15;
  const int px = blockIdx.x;
  const int p = (blockIdx.y & 16) ? (15 - px) : px;
  const int q0 = p * 128;
  const int nkt = 4 * (p + 1);  // # of 32-col K tiles (causal), >= 4

  const short* qbase = qkv + (size_t)b * 2048 * 6144 + h * 128;
  const short* kbase = qkv + (size_t)b * 2048 * 6144 + 2048 + h * 128;
  const short* vtbase = vT + (size_t)bh * 128 * 2048;
  short* obase = obuf + (size_t)b * 2048 * 2048 + h * 128;

  const int srow = lane >> 2;        // staging: row within 16-row chunk
  const int scol = (lane & 3) * 8;   // staging: col offset within 32-col chunk

  // ones B-fragment for row-sum MFMA (bf16 1.0 = 0x3F80)
  bf16x8 ones;
#pragma unroll
  for (int j = 0; j < 8; ++j) ones[j] = (short)0x3F80;

  // Q fragments resident: wave owns 16 q-rows, 4 d-chunks of 32
  bf16x8 qf[4];
#pragma unroll
  for (int kk = 0; kk < 4; ++kk)
    qf[kk] = *(const bf16x8*)(
        qbase + (size_t)(q0 + wave * 16 + l16) * 6144 + kk * 32 + quad * 8);

  f32x4 acco[8] = {};
  f32x4 accl = {};  // row-sum accumulator

  // stage K/V tile kt into buffer sb: per wave 2 loads (K chunk 'wave',
  // V chunk 'wave'). K chunk c: keys (c&1)*16+srow, d (c>>1)*32+scol.
  // V chunk c: d-rows c*16+srow, s-cols k0+scol. Chunk = [16][32] row-major.
  auto stage = [&](int sb, int kt) {
    const int k0 = kt * 32;
    gload_lds16(
        kbase + (size_t)(k0 + (wave & 1) * 16 + srow) * 6144 +
            (wave >> 1) * 32 + scol,
        (const char*)Ks + sb * 8192 + wave * 1024);
    gload_lds16(
        vtbase + (size_t)(wave * 16 + srow) * 2048 + k0 + scol,
        (const char*)Vs + sb * 8192 + wave * 1024);
  };

  // prologue: tiles 0,1,2 in flight (6 loads/wave outstanding)
  stage(0, 0);
  stage(1, (1 < nkt) ? 1 : nkt - 1);
  stage(2, (2 < nkt) ? 2 : nkt - 1);

  int buf = 0;
  for (int kt = 0; kt < nkt; ++kt) {
    const int st = (kt + 3 < nkt) ? (kt + 3) : (nkt - 1);  // clamped tail
    // tile kt's 2 loads are the oldest; leave tiles kt+1, kt+2 (4) in flight.
    asm volatile("s_waitcnt vmcnt(4)" ::: "memory");
    __builtin_amdgcn_s_barrier();
    stage((buf + 3) & 3, st);  // post-barrier prefetch of tile kt+3
    const short* KsB = Ks + buf * 4096;
    const short* VsB = Vs + buf * 4096;

    // ---- S = Q K^T (wave: its 16 q-rows x 32 keys; streamed K frags) ----
    f32x4 accs[2] = {};
#pragma unroll
    for (int kk = 0; kk < 4; ++kk)
#pragma unroll
      for (int tn = 0; tn < 2; ++tn) {
        bf16x8 kf = *(const bf16x8*)(KsB + (kk * 2 + tn) * 512 + l16 * 32 +
                                     quad * 8);
        accs[tn] = __builtin_amdgcn_mfma_f32_16x16x32_bf16(
            qf[kk], kf, accs[tn], 0, 0, 0);
      }

    // ---- causal mask (last four tiles straddle the diagonal) + exp2 ----
    if (kt >= nkt - 4) {
      const int k0 = kt * 32;
#pragma unroll
      for (int tn = 0; tn < 2; ++tn)
#pragma unroll
        for (int r = 0; r < 4; ++r) {
          int grow = q0 + wave * 16 + quad * 4 + r;
          int gcol = k0 + tn * 16 + l16;
          if (gcol > grow) accs[tn][r] = -1e30f;
        }
    }
#pragma unroll
    for (int tn = 0; tn < 2; ++tn)
#pragma unroll
      for (int r = 0; r < 4; ++r) accs[tn][r] = exp2f(accs[tn][r]);

    // ---- write P~ (A-frag row-major [16][32]) into wave-private Ps ----
#pragma unroll
    for (int r = 0; r < 4; ++r)
#pragma unroll
      for (int tn = 0; tn < 2; ++tn)
        Ps[wave * 512 + (quad * 4 + r) * 32 + tn * 16 + l16] =
            f2bf(accs[tn][r]);

    // ---- O += P~ V; row-sum += P~ @ ones (streamed V frags) ----
    bf16x8 av = *(const bf16x8*)(Ps + wave * 512 + l16 * 32 + quad * 8);
    accl = __builtin_amdgcn_mfma_f32_16x16x32_bf16(av, ones, accl, 0, 0, 0);
#pragma unroll
    for (int tn = 0; tn < 8; ++tn) {
      bf16x8 vv = *(const bf16x8*)(VsB + tn * 512 + l16 * 32 + quad * 8);
      acco[tn] = __builtin_amdgcn_mfma_f32_16x16x32_bf16(
          av, vv, acco[tn], 0, 0, 0);
    }

    buf = (buf + 1) & 3;
  }

  // drain clamped duplicate prefetch DMAs before exit
  asm volatile("s_waitcnt vmcnt(0)" ::: "memory");

  // ---- epilogue: O /= rowsum, store bf16 to (b, s, h*128+d) ----
  float inv[4];
#pragma unroll
  for (int r = 0; r < 4; ++r) inv[r] = 1.f / accl[r];
#pragma unroll
  for (int r = 0; r < 4; ++r) {
    int row = q0 + wave * 16 + quad * 4 + r;
#pragma unroll
    for (int tn = 0; tn < 8; ++tn)
      obase[(size_t)row * 2048 + tn * 16 + l16] = f2bf(acco[tn][r] * inv[r]);
  }
}

// ---------------------------------------------------------------------------
extern "C" void kernel_launch(void* const* d_in, const int* in_sizes, int n_in,
                              void* d_out, int out_size, void* d_ws,
                              size_t ws_size, hipStream_t stream) {
  (void)in_sizes; (void)n_in; (void)out_size; (void)ws_size;
  const float* x    = (const float*)d_in[0];
  const float* Wqkv = (const float*)d_in[1];
  const float* bqkv = (const float*)d_in[2];
  const float* Wout = (const float*)d_in[3];
  const float* bout = (const float*)d_in[4];
  float* out = (float*)d_out;

  char* ws = (char*)d_ws;
  short* xb    = (short*)(ws);                    // 16,777,216 B
  short* wqkvT = (short*)(ws + 16777216);         // 25,165,824 B
  short* woutT = (short*)(ws + 41943040);         //  8,388,608 B
  short* qkv   = (short*)(ws + 50331648);         // 50,331,648 B (V part unused)
  short* vTb   = (short*)(ws + 100663296);        // 16,777,216 B
  short* obuf  = (short*)(ws + 117440512);        // 16,777,216 B -> 128 MiB total

  // 1) casts / transposes
  cast_f32_bf16<<<4096, 256, 0, stream>>>(x, xb, 1048576);
  transpose_cast_w<<<dim3(64, 192), 256, 0, stream>>>(Wqkv, wqkvT, 2048, 6144);
  transpose_cast_w<<<dim3(64, 64), 256, 0, stream>>>(Wout, woutT, 2048, 2048);

  // 2) qkv = x @ W_qkv + b_qkv; Q cols pre-scaled, V cols -> vT (coalesced)
  //    grid 16x48 = 768 blocks (256x128 tiles) = 3 full CU-rounds
  gemm256<1, 1, 1><<<dim3(16, 48), 512, 0, stream>>>(
      xb, wqkvT, (void*)qkv, bqkv, vTb, 4096, 6144, 2048);

  // 3) attention: 512 blocks x 512 threads, 2 blocks/CU, 4-deep K/V pipeline
  attn_kernel<<<dim3(16, 32), 512, 0, stream>>>(qkv, vTb, obuf);

  // 4) y = O @ W_out + b_out   (M=4096, N=2048, K=2048) -> fp32
  gemm256<0, 0, 0><<<dim3(16, 16), 512, 0, stream>>>(
      obuf, woutT, (void*)out, bout, nullptr, 4096, 2048, 2048);
}